// Round 1
// baseline (162.070 us; speedup 1.0000x reference)
//
#include <hip/hip_runtime.h>
#include <stdint.h>

#define C 64
#define HH 112
#define WWD 112
#define HW (HH*WWD)
#define NB 32
#define MTOT (NB*HW)

// ---- K1: binarize weights: per-o scale = mean|w|, sign bits over input channel i per (kh,kw) pos
__global__ void k_prep_weights(const float* __restrict__ w, uint64_t* __restrict__ wbits,
                               float* __restrict__ wscale) {
    int o = threadIdx.x;
    if (o >= C) return;
    float s = 0.f;
    uint64_t bits[9] = {0,0,0,0,0,0,0,0,0};
    for (int i = 0; i < C; ++i) {
        #pragma unroll
        for (int pos = 0; pos < 9; ++pos) {
            float v = w[(o*C + i)*9 + pos];
            s += fabsf(v);
            bits[pos] |= (uint64_t)(v > 0.f) << i;
        }
    }
    wscale[o] = s * (1.0f/576.0f);
    #pragma unroll
    for (int pos = 0; pos < 9; ++pos) wbits[o*9+pos] = bits[pos];
}

// ---- K2: pack sign/nonzero bitplanes of sign(x + b0): bit c = channel c
__global__ void k_pack(const float* __restrict__ x, const float* __restrict__ b0,
                       uint64_t* __restrict__ xp, uint64_t* __restrict__ xz) {
    int n = blockIdx.y;
    int pix = blockIdx.x * blockDim.x + threadIdx.x;
    if (pix >= HW) return;
    uint64_t p = 0, z = 0;
    const float* xb = x + (size_t)n * C * HW + pix;
    #pragma unroll
    for (int c = 0; c < C; ++c) {
        float v = xb[(size_t)c * HW] + b0[c];
        p |= (uint64_t)(v > 0.f)  << c;
        z |= (uint64_t)(v != 0.f) << c;
    }
    xp[(size_t)n*HW + pix] = p;
    xz[(size_t)n*HW + pix] = z;
}

// ---- K3: XNOR-popcount conv 3x3 pad 1. Each thread = one pixel, loops 64 output channels.
__global__ void k_conv(const uint64_t* __restrict__ xp, const uint64_t* __restrict__ xz,
                       const uint64_t* __restrict__ wbits, const float* __restrict__ wscale,
                       float* __restrict__ cv) {
    __shared__ uint64_t sq[C*9];
    __shared__ float ss[C];
    for (int i = threadIdx.x; i < C*9; i += blockDim.x) sq[i] = wbits[i];
    for (int i = threadIdx.x; i < C;   i += blockDim.x) ss[i] = wscale[i];
    __syncthreads();
    int n = blockIdx.y;
    int pix = blockIdx.x * blockDim.x + threadIdx.x;
    if (pix >= HW) return;
    int h = pix / WWD, w = pix % WWD;
    uint64_t P[9], Z[9];
    {
        int k = 0;
        #pragma unroll
        for (int dh = -1; dh <= 1; ++dh) {
            #pragma unroll
            for (int dw = -1; dw <= 1; ++dw, ++k) {
                int hh = h + dh, ww = w + dw;
                bool ok = (hh >= 0) & (hh < HH) & (ww >= 0) & (ww < WWD);
                size_t idx = (size_t)n*HW + (size_t)hh*WWD + ww;
                P[k] = ok ? xp[idx] : 0ull;
                Z[k] = ok ? xz[idx] : 0ull;
            }
        }
    }
    int zsum = 0;
    #pragma unroll
    for (int k = 0; k < 9; ++k) zsum += __popcll(Z[k]);
    float* outp = cv + (size_t)n*C*HW + pix;
    for (int o = 0; o < C; ++o) {
        int acc = 0;
        #pragma unroll
        for (int k = 0; k < 9; ++k)
            acc += __popcll(Z[k] & (P[k] ^ sq[o*9+k]));
        outp[(size_t)o*HW] = ss[o] * (float)(zsum - 2*acc);
    }
}

// ---- K4: per-(o,n) block partial sum/sumsq of conv output (deterministic, no atomics)
__global__ void k_stats(const float* __restrict__ cv, float* __restrict__ psum,
                        float* __restrict__ psumsq) {
    int o = blockIdx.x & 63;
    int n = blockIdx.x >> 6;
    const float* p = cv + ((size_t)n*C + o) * HW;
    float s = 0.f, s2 = 0.f;
    for (int i = threadIdx.x; i < HW; i += blockDim.x) {
        float v = p[i];
        s += v; s2 += v*v;
    }
    __shared__ float ls[256], ls2[256];
    ls[threadIdx.x] = s; ls2[threadIdx.x] = s2;
    __syncthreads();
    for (int st = 128; st > 0; st >>= 1) {
        if ((int)threadIdx.x < st) {
            ls[threadIdx.x]  += ls[threadIdx.x+st];
            ls2[threadIdx.x] += ls2[threadIdx.x+st];
        }
        __syncthreads();
    }
    if (threadIdx.x == 0) { psum[o*NB + n] = ls[0]; psumsq[o*NB + n] = ls2[0]; }
}

// ---- K5: finalize BN affine per channel
__global__ void k_bnfin(const float* __restrict__ psum, const float* __restrict__ psumsq,
                        const float* __restrict__ gamma, const float* __restrict__ beta,
                        float* __restrict__ bnab) {
    int o = threadIdx.x;
    if (o >= C) return;
    float s = 0.f, s2 = 0.f;
    for (int n = 0; n < NB; ++n) { s += psum[o*NB+n]; s2 += psumsq[o*NB+n]; }
    float mean = s * (1.0f/(float)MTOT);
    float var  = s2 * (1.0f/(float)MTOT) - mean*mean;
    float a = gamma[o] * rsqrtf(var + 1e-5f);
    float b = beta[o] - mean * a;
    bnab[2*o]   = a;
    bnab[2*o+1] = b;
}

// ---- K6: fused BN + residual + b1 + PReLU + b2, in-place on d_out (cv)
__global__ void k_finish(const float* __restrict__ cv_in, const float* __restrict__ x,
                         const float* __restrict__ bnab, const float* __restrict__ b1,
                         const float* __restrict__ alpha, const float* __restrict__ b2,
                         float* __restrict__ out) {
    int o = blockIdx.x & 63;
    int n = blockIdx.x >> 6;
    float a   = bnab[2*o];
    float b   = bnab[2*o+1];
    float bb1 = b1[o];
    float al  = alpha[o];
    float bb2 = b2[o];
    size_t base = ((size_t)n*C + o) * HW;
    const float4* cvp = (const float4*)(cv_in + base);
    const float4* xp4 = (const float4*)(x + base);
    float4* op = (float4*)(out + base);
    for (int i = threadIdx.x; i < HW/4; i += blockDim.x) {
        float4 cvv = cvp[i], xv = xp4[i], r;
        float t;
        t = a*cvv.x + b + xv.x + bb1; t = t > 0.f ? t : al*t; r.x = t + bb2;
        t = a*cvv.y + b + xv.y + bb1; t = t > 0.f ? t : al*t; r.y = t + bb2;
        t = a*cvv.z + b + xv.z + bb1; t = t > 0.f ? t : al*t; r.z = t + bb2;
        t = a*cvv.w + b + xv.w + bb1; t = t > 0.f ? t : al*t; r.w = t + bb2;
        op[i] = r;
    }
}

extern "C" void kernel_launch(void* const* d_in, const int* in_sizes, int n_in,
                              void* d_out, int out_size, void* d_ws, size_t ws_size,
                              hipStream_t stream) {
    const float* x     = (const float*)d_in[0];
    const float* b0    = (const float*)d_in[1];
    const float* w     = (const float*)d_in[2];
    const float* gamma = (const float*)d_in[3];
    const float* beta  = (const float*)d_in[4];
    const float* b1    = (const float*)d_in[5];
    const float* alpha = (const float*)d_in[6];
    const float* b2    = (const float*)d_in[7];
    float* out = (float*)d_out;

    char* ws = (char*)d_ws;
    const size_t XPB = (size_t)NB * HW * sizeof(uint64_t);   // 3,211,264 B
    uint64_t* xp     = (uint64_t*)ws;
    uint64_t* xz     = (uint64_t*)(ws + XPB);
    uint64_t* wbits  = (uint64_t*)(ws + 2*XPB);
    float*    wscale = (float*)(ws + 2*XPB + C*9*sizeof(uint64_t));
    float*    psum   = wscale + C;
    float*    psumsq = psum + C*NB;
    float*    bnab   = psumsq + C*NB;

    hipLaunchKernelGGL(k_prep_weights, dim3(1), dim3(64), 0, stream, w, wbits, wscale);
    hipLaunchKernelGGL(k_pack, dim3(HW/256, NB), dim3(256), 0, stream, x, b0, xp, xz);
    hipLaunchKernelGGL(k_conv, dim3(HW/256, NB), dim3(256), 0, stream, xp, xz, wbits, wscale, out);
    hipLaunchKernelGGL(k_stats, dim3(C*NB), dim3(256), 0, stream, out, psum, psumsq);
    hipLaunchKernelGGL(k_bnfin, dim3(1), dim3(64), 0, stream, psum, psumsq, gamma, beta, bnab);
    hipLaunchKernelGGL(k_finish, dim3(C*NB), dim3(256), 0, stream, out, x, bnab, b1, alpha, b2, out);
}

// Round 2
// 132.896 us; speedup vs baseline: 1.2195x; 1.2195x over previous
//
#include <hip/hip_runtime.h>
#include <stdint.h>

#define C 64
#define HH 112
#define WWD 112
#define HW (HH*WWD)
#define NB 32
#define MTOT (NB*HW)
#define PPR 56        // pixel-pairs per row
#define PPI 6272      // pixel-pairs per image (HW/2)
#define PACK_BLKS 1568  // 32 images * 49 chunks of 256 pixels

// ---- K1: pack bitplanes (blocks 0..1567) + weight prep (blocks 1568..1631)
__global__ __launch_bounds__(256) void k_prep_pack(
        const float* __restrict__ x, const float* __restrict__ b0,
        const float* __restrict__ w,
        uint64_t* __restrict__ xp, uint64_t* __restrict__ xz,
        uint64_t* __restrict__ wbits, float* __restrict__ wscale) {
    int bid = blockIdx.x;
    if (bid < PACK_BLKS) {
        int n = bid / 49;
        int pix = (bid % 49) * 256 + threadIdx.x;
        uint64_t p = 0, z = 0;
        const float* xb = x + (size_t)n * C * HW + pix;
        #pragma unroll
        for (int c = 0; c < C; ++c) {
            float v = xb[(size_t)c * HW] + b0[c];
            p |= (uint64_t)(v > 0.f)  << c;
            z |= (uint64_t)(v != 0.f) << c;
        }
        xp[(size_t)n*HW + pix] = p;
        xz[(size_t)n*HW + pix] = z;
    } else {
        if (threadIdx.x >= 64) return;      // one wave
        int o = bid - PACK_BLKS;            // 0..63
        int i = threadIdx.x;                // input channel
        const float* wp = w + ((size_t)o*C + i)*9;
        float s = 0.f;
        uint64_t b[9];
        #pragma unroll
        for (int k = 0; k < 9; ++k) {
            float v = wp[k];
            s += fabsf(v);
            b[k] = __ballot(v > 0.f);
        }
        #pragma unroll
        for (int off = 32; off > 0; off >>= 1) s += __shfl_down(s, off);
        if (i == 0) {
            wscale[o] = s * (1.0f/576.0f);
            #pragma unroll
            for (int k = 0; k < 9; ++k) wbits[o*9+k] = b[k];
        }
    }
}

// ---- K2: XNOR-popcount conv, 2 pixels/thread, scalar (uniform) weight loads,
//          int16-pair output stored sparsely into d_out planes.
__global__ __launch_bounds__(256) void k_conv(
        const uint64_t* __restrict__ xp, const uint64_t* __restrict__ xz,
        const uint64_t* __restrict__ wbits, uint32_t* __restrict__ cv) {
    int n = blockIdx.y;
    int pr = blockIdx.x * blockDim.x + threadIdx.x;
    if (pr >= PPI) return;
    int row = pr / PPR;
    int j   = pr - row * PPR;
    int c0  = 2 * j;
    const size_t base = (size_t)n * HW;
    uint64_t P[12], Z[12];
    #pragma unroll
    for (int r = 0; r < 3; ++r) {
        int rr = row + r - 1;
        bool okr = (rr >= 0) & (rr < HH);
        #pragma unroll
        for (int c = 0; c < 4; ++c) {
            int cc = c0 + c - 1;
            bool ok = okr & (cc >= 0) & (cc < WWD);
            size_t idx = base + (size_t)rr * WWD + cc;
            P[r*4+c] = ok ? xp[idx] : 0ull;
            Z[r*4+c] = ok ? xz[idx] : 0ull;
        }
    }
    int zs0 = 0, zs1 = 0;
    #pragma unroll
    for (int r = 0; r < 3; ++r) {
        zs0 += __popcll(Z[r*4+0]) + __popcll(Z[r*4+1]) + __popcll(Z[r*4+2]);
        zs1 += __popcll(Z[r*4+1]) + __popcll(Z[r*4+2]) + __popcll(Z[r*4+3]);
    }
    // int16 plane p=(n*64+o) lives at dword offset p*HW (first 6272 dwords used)
    uint32_t* op = cv + (size_t)n * C * HW + pr;
    const uint64_t* wq = wbits;
    for (int o = 0; o < C; ++o) {
        int a0 = 0, a1 = 0;
        #pragma unroll
        for (int r = 0; r < 3; ++r) {
            #pragma unroll
            for (int c = 0; c < 3; ++c) {
                uint64_t q = wq[r*3+c];   // uniform -> s_load, SGPR operand
                a0 += __popcll(Z[r*4+c]   & (P[r*4+c]   ^ q));
                a1 += __popcll(Z[r*4+c+1] & (P[r*4+c+1] ^ q));
            }
        }
        int v0 = zs0 - 2*a0, v1 = zs1 - 2*a1;
        op[0] = (uint32_t)(uint16_t)v0 | ((uint32_t)(uint16_t)v1 << 16);
        op += HW;      // next o plane (sparse: planes are HW dwords apart)
        wq += 9;
    }
}

// ---- K3: per-(o,n) partial integer stats from int16 planes
__global__ __launch_bounds__(256) void k_stats(
        const uint32_t* __restrict__ cv, float* __restrict__ psum,
        float* __restrict__ psumsq) {
    int o = blockIdx.x & 63;
    int n = blockIdx.x >> 6;
    const uint32_t* p = cv + ((size_t)n * C + o) * HW;
    float s = 0.f, s2 = 0.f;
    for (int i = threadIdx.x; i < PPI/2; i += 256) {   // uint2 = 4 shorts
        uint2 u = ((const uint2*)p)[i];
        float v0 = (float)(int)(short)(u.x & 0xFFFF);
        float v1 = (float)(int)(short)(u.x >> 16);
        float v2 = (float)(int)(short)(u.y & 0xFFFF);
        float v3 = (float)(int)(short)(u.y >> 16);
        s  += (v0 + v1) + (v2 + v3);
        s2 += (v0*v0 + v1*v1) + (v2*v2 + v3*v3);
    }
    __shared__ float ls[256], ls2[256];
    ls[threadIdx.x] = s; ls2[threadIdx.x] = s2;
    __syncthreads();
    for (int st = 128; st > 0; st >>= 1) {
        if ((int)threadIdx.x < st) {
            ls[threadIdx.x]  += ls[threadIdx.x+st];
            ls2[threadIdx.x] += ls2[threadIdx.x+st];
        }
        __syncthreads();
    }
    if (threadIdx.x == 0) { psum[o*NB + n] = ls[0]; psumsq[o*NB + n] = ls2[0]; }
}

// ---- K4: BN finalize (redundant per block) + BN + residual + PReLU, LDS-staged in-place
__global__ __launch_bounds__(256) void k_finish(
        const uint32_t* cvi, const float* __restrict__ x,
        const float* __restrict__ psum, const float* __restrict__ psumsq,
        const float* __restrict__ wscale, const float* __restrict__ gamma,
        const float* __restrict__ beta, const float* __restrict__ b1,
        const float* __restrict__ alpha, const float* __restrict__ b2,
        float* out) {
    int o = blockIdx.x & 63;
    int n = blockIdx.x >> 6;
    size_t plane = (size_t)n * C + o;

    __shared__ uint32_t sk[PPI];
    const uint32_t* kp = cvi + plane * HW;
    for (int i = threadIdx.x; i < PPI; i += 256) sk[i] = kp[i];

    // per-channel BN affine, computed identically by every thread (uniform scalar loads)
    float s = 0.f, s2 = 0.f;
    #pragma unroll 8
    for (int t = 0; t < NB; ++t) { s += psum[o*NB+t]; s2 += psumsq[o*NB+t]; }
    const float inv = 1.0f / (float)MTOT;
    float sc  = wscale[o];
    float mu  = sc * (s * inv);
    float ek2 = (sc * sc) * (s2 * inv);
    float var = ek2 - mu * mu;
    float g   = gamma[o] * rsqrtf(var + 1e-5f);
    float A   = g * sc;
    float B   = beta[o] - g * mu + b1[o];
    float al  = alpha[o];
    float bb2 = b2[o];

    __syncthreads();

    const float4* xp4 = (const float4*)(x + plane * HW);
    float4* op = (float4*)(out + plane * HW);
    for (int i = threadIdx.x; i < HW/4; i += 256) {
        uint2 u = *(const uint2*)&sk[2*i];
        float4 xv = xp4[i], r;
        float t;
        t = A * (float)(int)(short)(u.x & 0xFFFF) + B + xv.x; t = t > 0.f ? t : al*t; r.x = t + bb2;
        t = A * (float)(int)(short)(u.x >> 16)    + B + xv.y; t = t > 0.f ? t : al*t; r.y = t + bb2;
        t = A * (float)(int)(short)(u.y & 0xFFFF) + B + xv.z; t = t > 0.f ? t : al*t; r.z = t + bb2;
        t = A * (float)(int)(short)(u.y >> 16)    + B + xv.w; t = t > 0.f ? t : al*t; r.w = t + bb2;
        op[i] = r;
    }
}

extern "C" void kernel_launch(void* const* d_in, const int* in_sizes, int n_in,
                              void* d_out, int out_size, void* d_ws, size_t ws_size,
                              hipStream_t stream) {
    const float* x     = (const float*)d_in[0];
    const float* b0    = (const float*)d_in[1];
    const float* w     = (const float*)d_in[2];
    const float* gamma = (const float*)d_in[3];
    const float* beta  = (const float*)d_in[4];
    const float* b1    = (const float*)d_in[5];
    const float* alpha = (const float*)d_in[6];
    const float* b2    = (const float*)d_in[7];

    char* ws = (char*)d_ws;
    const size_t XPB = (size_t)NB * HW * sizeof(uint64_t);   // 3,211,264 B
    uint64_t* xp     = (uint64_t*)ws;
    uint64_t* xz     = (uint64_t*)(ws + XPB);
    uint64_t* wbits  = (uint64_t*)(ws + 2*XPB);
    float*    wscale = (float*)(ws + 2*XPB + C*9*sizeof(uint64_t));
    float*    psum   = wscale + C;
    float*    psumsq = psum + C*NB;

    uint32_t* cv = (uint32_t*)d_out;

    hipLaunchKernelGGL(k_prep_pack, dim3(PACK_BLKS + 64), dim3(256), 0, stream,
                       x, b0, w, xp, xz, wbits, wscale);
    hipLaunchKernelGGL(k_conv, dim3((PPI + 255)/256, NB), dim3(256), 0, stream,
                       xp, xz, wbits, cv);
    hipLaunchKernelGGL(k_stats, dim3(C*NB), dim3(256), 0, stream, cv, psum, psumsq);
    hipLaunchKernelGGL(k_finish, dim3(C*NB), dim3(256), 0, stream,
                       cv, x, psum, psumsq, wscale, gamma, beta, b1, alpha, b2,
                       (float*)d_out);
}

// Round 3
// 113.570 us; speedup vs baseline: 1.4270x; 1.1702x over previous
//
#include <hip/hip_runtime.h>
#include <stdint.h>

#define C 64
#define HH 112
#define WWD 112
#define HW (HH*WWD)
#define NB 32
#define MTOT (NB*HW)
#define PPR 56          // pixel-pairs per row
#define PPI 6272        // pixel-pairs per image (HW/2)
#define PACK_BLKS 1568  // 32 images * 49 chunks of 256 pixels
#define OH 32           // output channels per conv block (o-split)

// ---- K1: pack sign bitplane (blocks 0..1567) + weight prep (blocks 1568..1631)
__global__ __launch_bounds__(256) void k_prep_pack(
        const float* __restrict__ x, const float* __restrict__ b0,
        const float* __restrict__ w,
        uint64_t* __restrict__ xp,
        uint64_t* __restrict__ wbits, float* __restrict__ wscale,
        int* __restrict__ corrP) {
    int bid = blockIdx.x;
    if (bid < PACK_BLKS) {
        int n = bid / 49;
        int pix = (bid % 49) * 256 + threadIdx.x;
        uint64_t p = 0;
        const float* xb = x + (size_t)n * C * HW + pix;
        #pragma unroll
        for (int c = 0; c < C; ++c) {
            float v = xb[(size_t)c * HW] + b0[c];
            p |= (uint64_t)(v > 0.f) << c;
        }
        xp[(size_t)n*HW + pix] = p;
    } else {
        if (threadIdx.x >= 64) return;      // one wave
        int o = bid - PACK_BLKS;            // 0..63
        int i = threadIdx.x;                // input channel
        const float* wp = w + ((size_t)o*C + i)*9;
        float s = 0.f;
        uint64_t b[9];
        #pragma unroll
        for (int k = 0; k < 9; ++k) {
            float v = wp[k];
            s += fabsf(v);
            b[k] = __ballot(v > 0.f);
        }
        #pragma unroll
        for (int off = 32; off > 0; off >>= 1) s += __shfl_down(s, off);
        if (i == 0) {
            wscale[o] = s * (1.0f/576.0f);
            int pq[9];
            #pragma unroll
            for (int k = 0; k < 9; ++k) {
                wbits[o*9+k] = b[k];
                pq[k] = __popcll(b[k]);
            }
            // corrP[region][o] = 576 - sum_{k in OOB(region)} (64 - 2*popcnt(q_k))
            for (int rc = 0; rc < 3; ++rc)
                for (int cc = 0; cc < 3; ++cc) {
                    int corr = 0;
                    for (int kr = 0; kr < 3; ++kr)
                        for (int kc = 0; kc < 3; ++kc) {
                            bool oob = (rc==0 && kr==0) || (rc==2 && kr==2) ||
                                       (cc==0 && kc==0) || (cc==2 && kc==2);
                            if (oob) corr += 64 - 2*pq[kr*3+kc];
                        }
                    corrP[(rc*3+cc)*C + o] = 576 - corr;
                }
        }
    }
}

// ---- K2: XNOR-popcount conv (no Z plane), 2 pixels/thread, o-split across z,
//          LDS weights + boundary-correction table, int16-pair stores.
__global__ __launch_bounds__(256) void k_conv(
        const uint64_t* __restrict__ xp, const uint64_t* __restrict__ wbits,
        const int* __restrict__ corrP, uint32_t* __restrict__ cv) {
    __shared__ uint64_t sq[OH*9];
    __shared__ int scor[9*OH];
    const int obase = blockIdx.z * OH;
    for (int i = threadIdx.x; i < OH*9; i += 256) sq[i] = wbits[obase*9 + i];
    for (int i = threadIdx.x; i < 9*OH; i += 256) {
        int r = i / OH, oo = i - r*OH;
        scor[i] = corrP[r*C + obase + oo];
    }
    __syncthreads();
    int n = blockIdx.y;
    int pr = blockIdx.x * 256 + threadIdx.x;
    if (pr >= PPI) return;
    int row = pr / PPR;
    int j   = pr - row * PPR;
    int c0  = 2 * j;
    const uint64_t* base = xp + (size_t)n * HW;
    uint64_t P[12];
    #pragma unroll
    for (int r = 0; r < 3; ++r) {
        int rr = row + r - 1;
        bool okr = (rr >= 0) & (rr < HH);
        #pragma unroll
        for (int c = 0; c < 4; ++c) {
            int cc = c0 + c - 1;
            bool ok = okr & (cc >= 0) & (cc < WWD);
            P[r*4+c] = ok ? base[(size_t)rr * WWD + cc] : 0ull;
        }
    }
    int rc  = (row == 0) ? 0 : ((row == HH-1) ? 2 : 1);
    int reg0 = (rc*3 + ((c0 == 0) ? 0 : 1)) * OH;        // pixel0: maybe left edge
    int reg1 = (rc*3 + ((c0 == WWD-2) ? 2 : 1)) * OH;    // pixel1: maybe right edge
    uint32_t* op = cv + ((size_t)n * C + obase) * HW + pr;
    for (int oo = 0; oo < OH; ++oo) {
        const uint64_t* q = &sq[oo*9];
        int a0 = 0, a1 = 0;
        #pragma unroll
        for (int r = 0; r < 3; ++r) {
            #pragma unroll
            for (int c = 0; c < 3; ++c) {
                uint64_t qk = q[r*3+c];
                a0 += __popcll(P[r*4+c]   ^ qk);
                a1 += __popcll(P[r*4+c+1] ^ qk);
            }
        }
        int v0 = scor[reg0 + oo] - 2*a0;
        int v1 = scor[reg1 + oo] - 2*a1;
        op[0] = (uint32_t)(uint16_t)v0 | ((uint32_t)(uint16_t)v1 << 16);
        op += HW;
    }
}

// ---- K3: per-(o,n) partial integer stats from int16 planes
__global__ __launch_bounds__(256) void k_stats(
        const uint32_t* __restrict__ cv, float* __restrict__ psum,
        float* __restrict__ psumsq) {
    int o = blockIdx.x & 63;
    int n = blockIdx.x >> 6;
    const uint32_t* p = cv + ((size_t)n * C + o) * HW;
    float s = 0.f, s2 = 0.f;
    for (int i = threadIdx.x; i < PPI/2; i += 256) {   // uint2 = 4 shorts
        uint2 u = ((const uint2*)p)[i];
        float v0 = (float)(int)(short)(u.x & 0xFFFF);
        float v1 = (float)(int)(short)(u.x >> 16);
        float v2 = (float)(int)(short)(u.y & 0xFFFF);
        float v3 = (float)(int)(short)(u.y >> 16);
        s  += (v0 + v1) + (v2 + v3);
        s2 += (v0*v0 + v1*v1) + (v2*v2 + v3*v3);
    }
    __shared__ float ls[256], ls2[256];
    ls[threadIdx.x] = s; ls2[threadIdx.x] = s2;
    __syncthreads();
    for (int st = 128; st > 0; st >>= 1) {
        if ((int)threadIdx.x < st) {
            ls[threadIdx.x]  += ls[threadIdx.x+st];
            ls2[threadIdx.x] += ls2[threadIdx.x+st];
        }
        __syncthreads();
    }
    if (threadIdx.x == 0) { psum[o*NB + n] = ls[0]; psumsq[o*NB + n] = ls2[0]; }
}

// ---- K4: BN finalize (redundant per block) + BN + residual + PReLU, LDS-staged in-place
__global__ __launch_bounds__(256) void k_finish(
        const uint32_t* cvi, const float* __restrict__ x,
        const float* __restrict__ psum, const float* __restrict__ psumsq,
        const float* __restrict__ wscale, const float* __restrict__ gamma,
        const float* __restrict__ beta, const float* __restrict__ b1,
        const float* __restrict__ alpha, const float* __restrict__ b2,
        float* out) {
    int o = blockIdx.x & 63;
    int n = blockIdx.x >> 6;
    size_t plane = (size_t)n * C + o;

    __shared__ uint32_t sk[PPI];
    const uint32_t* kp = cvi + plane * HW;
    for (int i = threadIdx.x; i < PPI; i += 256) sk[i] = kp[i];

    float s = 0.f, s2 = 0.f;
    #pragma unroll 8
    for (int t = 0; t < NB; ++t) { s += psum[o*NB+t]; s2 += psumsq[o*NB+t]; }
    const float inv = 1.0f / (float)MTOT;
    float sc  = wscale[o];
    float mu  = sc * (s * inv);
    float ek2 = (sc * sc) * (s2 * inv);
    float var = ek2 - mu * mu;
    float g   = gamma[o] * rsqrtf(var + 1e-5f);
    float A   = g * sc;
    float B   = beta[o] - g * mu + b1[o];
    float al  = alpha[o];
    float bb2 = b2[o];

    __syncthreads();

    const float4* xp4 = (const float4*)(x + plane * HW);
    float4* op = (float4*)(out + plane * HW);
    for (int i = threadIdx.x; i < HW/4; i += 256) {
        uint2 u = *(const uint2*)&sk[2*i];
        float4 xv = xp4[i], r;
        float t;
        t = A * (float)(int)(short)(u.x & 0xFFFF) + B + xv.x; t = t > 0.f ? t : al*t; r.x = t + bb2;
        t = A * (float)(int)(short)(u.x >> 16)    + B + xv.y; t = t > 0.f ? t : al*t; r.y = t + bb2;
        t = A * (float)(int)(short)(u.y & 0xFFFF) + B + xv.z; t = t > 0.f ? t : al*t; r.z = t + bb2;
        t = A * (float)(int)(short)(u.y >> 16)    + B + xv.w; t = t > 0.f ? t : al*t; r.w = t + bb2;
        op[i] = r;
    }
}

extern "C" void kernel_launch(void* const* d_in, const int* in_sizes, int n_in,
                              void* d_out, int out_size, void* d_ws, size_t ws_size,
                              hipStream_t stream) {
    const float* x     = (const float*)d_in[0];
    const float* b0    = (const float*)d_in[1];
    const float* w     = (const float*)d_in[2];
    const float* gamma = (const float*)d_in[3];
    const float* beta  = (const float*)d_in[4];
    const float* b1    = (const float*)d_in[5];
    const float* alpha = (const float*)d_in[6];
    const float* b2    = (const float*)d_in[7];

    char* ws = (char*)d_ws;
    const size_t XPB = (size_t)NB * HW * sizeof(uint64_t);   // 3,211,264 B
    uint64_t* xp     = (uint64_t*)ws;
    uint64_t* wbits  = (uint64_t*)(ws + XPB);
    float*    wscale = (float*)(ws + XPB + C*9*sizeof(uint64_t));
    int*      corrP  = (int*)(wscale + C);
    float*    psum   = (float*)(corrP + 9*C);
    float*    psumsq = psum + C*NB;

    uint32_t* cv = (uint32_t*)d_out;

    hipLaunchKernelGGL(k_prep_pack, dim3(PACK_BLKS + 64), dim3(256), 0, stream,
                       x, b0, w, xp, wbits, wscale, corrP);
    hipLaunchKernelGGL(k_conv, dim3((PPI + 255)/256, NB, 2), dim3(256), 0, stream,
                       xp, wbits, corrP, cv);
    hipLaunchKernelGGL(k_stats, dim3(C*NB), dim3(256), 0, stream, cv, psum, psumsq);
    hipLaunchKernelGGL(k_finish, dim3(C*NB), dim3(256), 0, stream,
                       cv, x, psum, psumsq, wscale, gamma, beta, b1, alpha, b2,
                       (float*)d_out);
}